// Round 8
// baseline (160.386 us; speedup 1.0000x reference)
//
#include <hip/hip_runtime.h>
#include <hip/hip_bf16.h>

#define BATCH 32
#define CIN   64
#define COUT  64
#define NFFT  4096
#define MODES 1024
#define KOUT  2049   // N/2 + 1
#define NPAD  2112   // 33 tiles of 64 cols

typedef __bf16 bf16x8 __attribute__((ext_vector_type(8)));
typedef float  f32x4  __attribute__((ext_vector_type(4)));

#define AS1 __attribute__((address_space(1)))
#define AS3 __attribute__((address_space(3)))

static __device__ __forceinline__ void gl_lds16(const void* g, void* l) {
    __builtin_amdgcn_global_load_lds((const AS1 void*)g, (AS3 void*)l, 16, 0, 0);
}

static __device__ __forceinline__ float bf2f(unsigned short s) {
    return __uint_as_float(((unsigned)s) << 16);
}
static __device__ __forceinline__ void cvt8(bf16x8 v, f32x4& lo, f32x4& hi) {
    union { bf16x8 b; unsigned short s[8]; } u;
    u.b = v;
    lo = (f32x4){bf2f(u.s[0]), bf2f(u.s[1]), bf2f(u.s[2]), bf2f(u.s[3])};
    hi = (f32x4){bf2f(u.s[4]), bf2f(u.s[5]), bf2f(u.s[6]), bf2f(u.s[7])};
}
static __device__ __forceinline__ bf16x8 pack8(f32x4 lo, f32x4 hi) {
    union { bf16x8 b; unsigned short s[8]; } u;
    __hip_bfloat16 h;
    h = __float2bfloat16(lo.x); u.s[0] = *(unsigned short*)&h;
    h = __float2bfloat16(lo.y); u.s[1] = *(unsigned short*)&h;
    h = __float2bfloat16(lo.z); u.s[2] = *(unsigned short*)&h;
    h = __float2bfloat16(lo.w); u.s[3] = *(unsigned short*)&h;
    h = __float2bfloat16(hi.x); u.s[4] = *(unsigned short*)&h;
    h = __float2bfloat16(hi.y); u.s[5] = *(unsigned short*)&h;
    h = __float2bfloat16(hi.z); u.s[6] = *(unsigned short*)&h;
    h = __float2bfloat16(hi.w); u.s[7] = *(unsigned short*)&h;
    return u.b;
}

// radix-4 butterfly (two fused radix-2 stages of the reference recursion)
static __device__ __forceinline__ void bfly4(float eA, float eB, float oA, float oB,
                                             float t, float c0, float c1,
                                             float& w0, float& w1, float& w2, float& w3) {
    float PA = fmaf(t, oA, eA), MA = fmaf(-t, oA, eA);
    float PB = fmaf(t, oB, eB), MB = fmaf(-t, oB, eB);
    w0 = fmaf(c0, PB, PA);
    w2 = fmaf(-c0, PB, PA);
    w1 = fmaf(c1, MB, MA);
    w3 = fmaf(-c1, MB, MA);
}

// ---------------- fill: tw table + C2^T in MFMA-fragment order ----------------
#define NCHUNK ((NPAD / 16) * (MODES / 32) * 64)   // 270336

__global__ void fill_tables(float* __restrict__ tw, __hip_bfloat16* __restrict__ c2f) {
    int gid = blockIdx.x * 256 + threadIdx.x;
    if (gid < NCHUNK) {
        int nl  = gid & 15;
        int kc  = (gid >> 4) & 3;
        int blk = gid >> 6;
        int kb  = blk & 31;
        int gn  = blk >> 5;
        int n = gn * 16 + nl;
        int kbase = kb * 32 + kc * 8;
        unsigned short v8[8];
        if (n < KOUT) {
#pragma unroll
            for (int j = 0; j < 8; ++j) {
                int k = kbase + j;
                int m = (k * n) % KOUT;
                float ang = 6.28318530717958647692f * (float)m / (float)KOUT;
                float v = (cosf(ang) + sinf(ang)) * (1.0f / (float)KOUT);
                __hip_bfloat16 h = __float2bfloat16(v);
                v8[j] = *(unsigned short*)&h;
            }
        } else {
#pragma unroll
            for (int j = 0; j < 8; ++j) v8[j] = 0;
        }
        *(ushort4*)((char*)c2f + (size_t)gid * 16)     = make_ushort4(v8[0], v8[1], v8[2], v8[3]);
        *(ushort4*)((char*)c2f + (size_t)gid * 16 + 8) = make_ushort4(v8[4], v8[5], v8[6], v8[7]);
    } else {
        int t = gid - NCHUNK;
        if (t < NFFT) {
            if (t == 0) { tw[0] = 1.0f; return; }
            int h = 1 << (31 - __clz(t));
            int n = t - h;
            float ang = 3.14159265358979323846f * (float)n / (float)h;
            tw[t] = cosf(ang) + sinf(ang);
        }
    }
}

// ---------------- stage 1: recursive "FHT", register radix-16; bf16 output ----------------
__global__ __launch_bounds__(256) void fht_kernel(const float* __restrict__ x,
                                                  const float* __restrict__ tw,
                                                  __hip_bfloat16* __restrict__ xh) {
    __shared__ float ldsA[4352];
    __shared__ float ldsB[4352];
    const int t = threadIdx.x;
    const int row = blockIdx.x;
    const float* xr = x + (size_t)row * NFFT;

    float r[4][4];
#pragma unroll
    for (int a = 0; a < 4; ++a)
#pragma unroll
        for (int c = 0; c < 4; ++c)
            r[a][c] = xr[t + 256 * a + 1024 * c];

    float o1[4][4];
#pragma unroll
    for (int a = 0; a < 4; ++a) {     // p=0: twiddles all 1
        float PA = r[a][0] + r[a][2], MA = r[a][0] - r[a][2];
        float PB = r[a][1] + r[a][3], MB = r[a][1] - r[a][3];
        o1[a][0] = PA + PB;
        o1[a][2] = PA - PB;
        o1[a][1] = MA + MB;
        o1[a][3] = MA - MB;
    }
    float o2[4][4];
#pragma unroll
    for (int kap = 0; kap < 4; ++kap) {
        float tt = tw[4 + kap], c0 = tw[8 + kap], c1 = tw[12 + kap];
        bfly4(o1[0][kap], o1[1][kap], o1[2][kap], o1[3][kap], tt, c0, c1,
              o2[kap][0], o2[kap][1], o2[kap][2], o2[kap][3]);
    }
#pragma unroll
    for (int kap = 0; kap < 4; ++kap)
#pragma unroll
        for (int c = 0; c < 4; ++c) {
            int p = t + 256 * kap + 1024 * c;
            ldsA[p + (p >> 4)] = o2[kap][c];
        }
    __syncthreads();

    const int kap2 = t >> 4, gp = t & 15;
    float r2[4][4];
#pragma unroll
    for (int a = 0; a < 4; ++a)
#pragma unroll
        for (int c = 0; c < 4; ++c) {
            int p = 256 * kap2 + gp + 16 * a + 64 * c;
            r2[a][c] = ldsA[p + (p >> 4)];
        }
    float o3[4][4];
    {
        float tt = tw[16 + kap2], c0 = tw[32 + kap2], c1 = tw[48 + kap2];
#pragma unroll
        for (int a = 0; a < 4; ++a)
            bfly4(r2[a][0], r2[a][1], r2[a][2], r2[a][3], tt, c0, c1,
                  o3[a][0], o3[a][1], o3[a][2], o3[a][3]);
    }
    float o4[4][4];
#pragma unroll
    for (int c = 0; c < 4; ++c) {
        int kap3 = kap2 + 16 * c;
        float tt = tw[64 + kap3], c0 = tw[128 + kap3], c1 = tw[192 + kap3];
        bfly4(o3[0][c], o3[1][c], o3[2][c], o3[3][c], tt, c0, c1,
              o4[c][0], o4[c][1], o4[c][2], o4[c][3]);
    }
#pragma unroll
    for (int c = 0; c < 4; ++c)
#pragma unroll
        for (int cc = 0; cc < 4; ++cc) {
            int p = t + 256 * c + 1024 * cc;
            ldsB[p + (p >> 4)] = o4[c][cc];
        }
    __syncthreads();

    float r3[4][4];
#pragma unroll
    for (int g = 0; g < 4; ++g)
#pragma unroll
        for (int c = 0; c < 4; ++c) {
            int p = 16 * t + g + 4 * c;
            r3[g][c] = ldsB[p + (p >> 4)];
        }
    float o5[4][4];
    {
        float tt = tw[256 + t], c0 = tw[512 + t], c1 = tw[768 + t];
#pragma unroll
        for (int g = 0; g < 4; ++g)
            bfly4(r3[g][0], r3[g][1], r3[g][2], r3[g][3], tt, c0, c1,
                  o5[g][0], o5[g][1], o5[g][2], o5[g][3]);
    }
    __hip_bfloat16* xo = xh + (size_t)row * MODES;
#pragma unroll
    for (int c = 0; c < 4; ++c) {
        float tt = tw[1024 + t + 256 * c];
        float c0 = tw[2048 + t + 256 * c];
        float PA = fmaf(tt, o5[2][c], o5[0][c]);
        float PB = fmaf(tt, o5[3][c], o5[1][c]);
        xo[t + 256 * c] = __float2bfloat16(fmaf(c0, PB, PA));
    }
}

// ---------------- stage 2: channel mix, reuse-blocked ----------------
// grid (kt=64 k-stripes of 16, bpg=2, oz=2); block 512 = (kl:2, og:32, bpl:8 [wave]).
// w redundancy 2x (33.6 MB), xh redundancy 2x (8.4 MB) -> ~42 MB L2 total.
__global__ __launch_bounds__(512) void mix_kernel(const __hip_bfloat16* __restrict__ xh,
                                                  const float* __restrict__ w,
                                                  __hip_bfloat16* __restrict__ y) {
    const int tid = threadIdx.x;
    const int kl  = tid & 1;
    const int og  = (tid >> 1) & 31;
    const int bpl = tid >> 6;                 // wave id 0..7
    const int bp  = blockIdx.y * 8 + bpl;     // b-pair 0..15
    const int rb  = (BATCH - 1) - bp;
    const int o   = blockIdx.z * 32 + og;
    const int k8  = blockIdx.x * 2 + kl;      // bf16x8 window 0..127

    f32x4 accb0 = {0,0,0,0}, accb1 = {0,0,0,0};
    f32x4 accr0 = {0,0,0,0}, accr1 = {0,0,0,0};

    const __hip_bfloat16* xb  = xh + (size_t)(bp * CIN) * MODES + k8 * 8;
    const __hip_bfloat16* xrb = xh + (size_t)(rb * CIN) * MODES + k8 * 8;
    const float* wo = w + (size_t)o * MODES + k8 * 8;

#pragma unroll 4
    for (int i = 0; i < 32; ++i) {
        const int mi = 63 - i;
        bf16x8 xai = *(const bf16x8*)(xb  + (size_t)i  * MODES);
        bf16x8 xam = *(const bf16x8*)(xb  + (size_t)mi * MODES);
        bf16x8 xbi = *(const bf16x8*)(xrb + (size_t)i  * MODES);
        bf16x8 xbm = *(const bf16x8*)(xrb + (size_t)mi * MODES);
        f32x4 w1a = *(const f32x4*)(wo + (size_t)(i  * COUT) * MODES);
        f32x4 w1b = *(const f32x4*)(wo + (size_t)(i  * COUT) * MODES + 4);
        f32x4 w2a = *(const f32x4*)(wo + (size_t)(mi * COUT) * MODES);
        f32x4 w2b = *(const f32x4*)(wo + (size_t)(mi * COUT) * MODES + 4);

        f32x4 ai_lo, ai_hi, am_lo, am_hi, bi_lo, bi_hi, bm_lo, bm_hi;
        cvt8(xai, ai_lo, ai_hi);
        cvt8(xam, am_lo, am_hi);
        cvt8(xbi, bi_lo, bi_hi);
        cvt8(xbm, bm_lo, bm_hi);

        f32x4 sa0 = ai_lo + am_lo, sa1 = ai_hi + am_hi;
        f32x4 da0 = ai_lo - am_lo, da1 = ai_hi - am_hi;
        f32x4 sb0 = bi_lo + bm_lo, sb1 = bi_hi + bm_hi;
        f32x4 db0 = bi_lo - bm_lo, db1 = bi_hi - bm_hi;
        f32x4 wp0 = w1a + w2a, wm0 = w1a - w2a;
        f32x4 wp1 = w1b + w2b, wm1 = w1b - w2b;

        accb0 += sa0 * wp0 + db0 * wm0;
        accb1 += sa1 * wp1 + db1 * wm1;
        accr0 += sb0 * wp0 + da0 * wm0;
        accr1 += sb1 * wp1 + da1 * wm1;
    }

    bf16x8 vb = pack8(accb0 * 0.5f, accb1 * 0.5f);
    bf16x8 vr = pack8(accr0 * 0.5f, accr1 * 0.5f);
    *(bf16x8*)(y + (size_t)(bp * COUT + o) * MODES + k8 * 8) = vb;
    *(bf16x8*)(y + (size_t)(rb * COUT + o) * MODES + k8 * 8) = vr;
}

// ---------------- stage 3: iDHT MFMA GEMM (unchanged from R7) ----------------
__global__ __launch_bounds__(128) void idht_mfma(const __hip_bfloat16* __restrict__ yh,
                                                 const __hip_bfloat16* __restrict__ c2f,
                                                 float* __restrict__ out) {
    __shared__ __align__(16) char sa[2][4 * 1024];

    const int tid  = threadIdx.x;
    const int lane = tid & 63;
    const int wave = tid >> 6;
    const int rbase = blockIdx.x * 64;
    const int gn0   = blockIdx.y * 4;
    const int nbase = gn0 * 16;

    const int lrow = (lane & 15) * 2048;
    const int lchk = (lane >> 4) * 16;

    const char* ga = (const char*)yh + (size_t)rbase * 2048;
    const char* gb = (const char*)c2f;

    f32x4 acc[2][4];
#pragma unroll
    for (int mt = 0; mt < 2; ++mt)
#pragma unroll
        for (int nt = 0; nt < 4; ++nt) acc[mt][nt] = (f32x4){0.f, 0.f, 0.f, 0.f};

    auto stageA = [&](int bi, int k0) {
#pragma unroll
        for (int r = 0; r < 2; ++r) {
            int g = wave * 2 + r;
            gl_lds16(ga + (size_t)(g * 16) * 2048 + lrow + lchk + k0 * 2,
                     sa[bi] + g * 1024);
        }
    };
    auto loadB = [&](int ks, bf16x8* b_) {
#pragma unroll
        for (int nt = 0; nt < 4; ++nt) {
            size_t ch = ((size_t)(gn0 + nt) * 32 + ks) * 64 + lane;
            b_[nt] = *(const bf16x8*)(gb + ch * 16);
        }
    };

    stageA(0, 0);
    bf16x8 bcur[4];
    loadB(0, bcur);
    int cur = 0;
    for (int ks = 0; ks < MODES / 32; ++ks) {
        __syncthreads();
        if (ks + 1 < MODES / 32) stageA(cur ^ 1, (ks + 1) * 32);
        bf16x8 bnext[4];
        int kn = (ks + 1 < MODES / 32) ? ks + 1 : ks;
        loadB(kn, bnext);
        bf16x8 a_[2];
#pragma unroll
        for (int mt = 0; mt < 2; ++mt)
            a_[mt] = *(const bf16x8*)(sa[cur] + (wave * 2 + mt) * 1024 + lane * 16);
#pragma unroll
        for (int mt = 0; mt < 2; ++mt)
#pragma unroll
            for (int nt = 0; nt < 4; ++nt)
                acc[mt][nt] = __builtin_amdgcn_mfma_f32_16x16x32_bf16(a_[mt], bcur[nt], acc[mt][nt], 0, 0, 0);
#pragma unroll
        for (int nt = 0; nt < 4; ++nt) bcur[nt] = bnext[nt];
        cur ^= 1;
    }

#pragma unroll
    for (int mt = 0; mt < 2; ++mt) {
        int row = rbase + wave * 32 + mt * 16 + (lane >> 4) * 4;
#pragma unroll
        for (int nt = 0; nt < 4; ++nt) {
            int col = nbase + nt * 16 + (lane & 15);
            if (col < KOUT) {
#pragma unroll
                for (int r = 0; r < 4; ++r)
                    out[(size_t)(row + r) * KOUT + col] = acc[mt][nt][r];
            }
        }
    }
}

// ---------------- launch ----------------
extern "C" void kernel_launch(void* const* d_in, const int* in_sizes, int n_in,
                              void* d_out, int out_size, void* d_ws, size_t ws_size,
                              hipStream_t stream) {
    const float* x = (const float*)d_in[0];     // (32, 64, 4096)
    const float* w = (const float*)d_in[1];     // (64, 64, 1024)
    float* out = (float*)d_out;                 // (32, 64, 2049)

    float* tw = (float*)d_ws;                                  // 4096 f32
    __hip_bfloat16* xh  = (__hip_bfloat16*)(tw + NFFT);        // 2048*1024 bf16
    __hip_bfloat16* y   = xh + (size_t)BATCH * CIN * MODES;    // 2048*1024 bf16
    __hip_bfloat16* c2f = y + (size_t)BATCH * COUT * MODES;    // NPAD*1024 bf16

    fill_tables<<<(NCHUNK + NFFT + 255) / 256, 256, 0, stream>>>(tw, c2f);
    fht_kernel<<<BATCH * CIN, 256, 0, stream>>>(x, tw, xh);
    mix_kernel<<<dim3(64, 2, 2), 512, 0, stream>>>(xh, w, y);
    idht_mfma<<<dim3((BATCH * COUT) / 64, NPAD / 64), 128, 0, stream>>>(y, c2f, out);
}

// Round 9
// 145.991 us; speedup vs baseline: 1.0986x; 1.0986x over previous
//
#include <hip/hip_runtime.h>
#include <hip/hip_bf16.h>

#define BATCH 32
#define CIN   64
#define COUT  64
#define NFFT  4096
#define MODES 1024
#define KOUT  2049   // N/2 + 1
#define NPAD  2112   // 33 tiles of 64 cols

typedef __bf16 bf16x8 __attribute__((ext_vector_type(8)));
typedef float  f32x4  __attribute__((ext_vector_type(4)));

static __device__ __forceinline__ float bf2f(unsigned short s) {
    return __uint_as_float(((unsigned)s) << 16);
}
static __device__ __forceinline__ void cvt8(bf16x8 v, f32x4& lo, f32x4& hi) {
    union { bf16x8 b; unsigned short s[8]; } u;
    u.b = v;
    lo = (f32x4){bf2f(u.s[0]), bf2f(u.s[1]), bf2f(u.s[2]), bf2f(u.s[3])};
    hi = (f32x4){bf2f(u.s[4]), bf2f(u.s[5]), bf2f(u.s[6]), bf2f(u.s[7])};
}
static __device__ __forceinline__ bf16x8 pack8(f32x4 lo, f32x4 hi) {
    union { bf16x8 b; unsigned short s[8]; } u;
    __hip_bfloat16 h;
    h = __float2bfloat16(lo.x); u.s[0] = *(unsigned short*)&h;
    h = __float2bfloat16(lo.y); u.s[1] = *(unsigned short*)&h;
    h = __float2bfloat16(lo.z); u.s[2] = *(unsigned short*)&h;
    h = __float2bfloat16(lo.w); u.s[3] = *(unsigned short*)&h;
    h = __float2bfloat16(hi.x); u.s[4] = *(unsigned short*)&h;
    h = __float2bfloat16(hi.y); u.s[5] = *(unsigned short*)&h;
    h = __float2bfloat16(hi.z); u.s[6] = *(unsigned short*)&h;
    h = __float2bfloat16(hi.w); u.s[7] = *(unsigned short*)&h;
    return u.b;
}

// radix-4 butterfly (two fused radix-2 stages of the reference recursion)
static __device__ __forceinline__ void bfly4(float eA, float eB, float oA, float oB,
                                             float t, float c0, float c1,
                                             float& w0, float& w1, float& w2, float& w3) {
    float PA = fmaf(t, oA, eA), MA = fmaf(-t, oA, eA);
    float PB = fmaf(t, oB, eB), MB = fmaf(-t, oB, eB);
    w0 = fmaf(c0, PB, PA);
    w2 = fmaf(-c0, PB, PA);
    w1 = fmaf(c1, MB, MA);
    w3 = fmaf(-c1, MB, MA);
}

// ---------------- fill: tw table + C2^T in MFMA-fragment order ----------------
#define NCHUNK ((NPAD / 16) * (MODES / 32) * 64)   // 270336

__global__ void fill_tables(float* __restrict__ tw, __hip_bfloat16* __restrict__ c2f) {
    int gid = blockIdx.x * 256 + threadIdx.x;
    if (gid < NCHUNK) {
        int nl  = gid & 15;
        int kc  = (gid >> 4) & 3;
        int blk = gid >> 6;
        int kb  = blk & 31;
        int gn  = blk >> 5;
        int n = gn * 16 + nl;
        int kbase = kb * 32 + kc * 8;
        unsigned short v8[8];
        if (n < KOUT) {
#pragma unroll
            for (int j = 0; j < 8; ++j) {
                int k = kbase + j;
                int m = (k * n) % KOUT;
                float ang = 6.28318530717958647692f * (float)m / (float)KOUT;
                float v = (cosf(ang) + sinf(ang)) * (1.0f / (float)KOUT);
                __hip_bfloat16 h = __float2bfloat16(v);
                v8[j] = *(unsigned short*)&h;
            }
        } else {
#pragma unroll
            for (int j = 0; j < 8; ++j) v8[j] = 0;
        }
        *(ushort4*)((char*)c2f + (size_t)gid * 16)     = make_ushort4(v8[0], v8[1], v8[2], v8[3]);
        *(ushort4*)((char*)c2f + (size_t)gid * 16 + 8) = make_ushort4(v8[4], v8[5], v8[6], v8[7]);
    } else {
        int t = gid - NCHUNK;
        if (t < NFFT) {
            if (t == 0) { tw[0] = 1.0f; return; }
            int h = 1 << (31 - __clz(t));
            int n = t - h;
            float ang = 3.14159265358979323846f * (float)n / (float)h;
            tw[t] = cosf(ang) + sinf(ang);
        }
    }
}

// ---------------- stage 1: recursive "FHT", register radix-16; bf16 output ----------------
__global__ __launch_bounds__(256) void fht_kernel(const float* __restrict__ x,
                                                  const float* __restrict__ tw,
                                                  __hip_bfloat16* __restrict__ xh) {
    __shared__ float ldsA[4352];
    __shared__ float ldsB[4352];
    const int t = threadIdx.x;
    const int row = blockIdx.x;
    const float* xr = x + (size_t)row * NFFT;

    float r[4][4];
#pragma unroll
    for (int a = 0; a < 4; ++a)
#pragma unroll
        for (int c = 0; c < 4; ++c)
            r[a][c] = xr[t + 256 * a + 1024 * c];

    float o1[4][4];
#pragma unroll
    for (int a = 0; a < 4; ++a) {     // p=0: twiddles all 1
        float PA = r[a][0] + r[a][2], MA = r[a][0] - r[a][2];
        float PB = r[a][1] + r[a][3], MB = r[a][1] - r[a][3];
        o1[a][0] = PA + PB;
        o1[a][2] = PA - PB;
        o1[a][1] = MA + MB;
        o1[a][3] = MA - MB;
    }
    float o2[4][4];
#pragma unroll
    for (int kap = 0; kap < 4; ++kap) {
        float tt = tw[4 + kap], c0 = tw[8 + kap], c1 = tw[12 + kap];
        bfly4(o1[0][kap], o1[1][kap], o1[2][kap], o1[3][kap], tt, c0, c1,
              o2[kap][0], o2[kap][1], o2[kap][2], o2[kap][3]);
    }
#pragma unroll
    for (int kap = 0; kap < 4; ++kap)
#pragma unroll
        for (int c = 0; c < 4; ++c) {
            int p = t + 256 * kap + 1024 * c;
            ldsA[p + (p >> 4)] = o2[kap][c];
        }
    __syncthreads();

    const int kap2 = t >> 4, gp = t & 15;
    float r2[4][4];
#pragma unroll
    for (int a = 0; a < 4; ++a)
#pragma unroll
        for (int c = 0; c < 4; ++c) {
            int p = 256 * kap2 + gp + 16 * a + 64 * c;
            r2[a][c] = ldsA[p + (p >> 4)];
        }
    float o3[4][4];
    {
        float tt = tw[16 + kap2], c0 = tw[32 + kap2], c1 = tw[48 + kap2];
#pragma unroll
        for (int a = 0; a < 4; ++a)
            bfly4(r2[a][0], r2[a][1], r2[a][2], r2[a][3], tt, c0, c1,
                  o3[a][0], o3[a][1], o3[a][2], o3[a][3]);
    }
    float o4[4][4];
#pragma unroll
    for (int c = 0; c < 4; ++c) {
        int kap3 = kap2 + 16 * c;
        float tt = tw[64 + kap3], c0 = tw[128 + kap3], c1 = tw[192 + kap3];
        bfly4(o3[0][c], o3[1][c], o3[2][c], o3[3][c], tt, c0, c1,
              o4[c][0], o4[c][1], o4[c][2], o4[c][3]);
    }
#pragma unroll
    for (int c = 0; c < 4; ++c)
#pragma unroll
        for (int cc = 0; cc < 4; ++cc) {
            int p = t + 256 * c + 1024 * cc;
            ldsB[p + (p >> 4)] = o4[c][cc];
        }
    __syncthreads();

    float r3[4][4];
#pragma unroll
    for (int g = 0; g < 4; ++g)
#pragma unroll
        for (int c = 0; c < 4; ++c) {
            int p = 16 * t + g + 4 * c;
            r3[g][c] = ldsB[p + (p >> 4)];
        }
    float o5[4][4];
    {
        float tt = tw[256 + t], c0 = tw[512 + t], c1 = tw[768 + t];
#pragma unroll
        for (int g = 0; g < 4; ++g)
            bfly4(r3[g][0], r3[g][1], r3[g][2], r3[g][3], tt, c0, c1,
                  o5[g][0], o5[g][1], o5[g][2], o5[g][3]);
    }
    __hip_bfloat16* xo = xh + (size_t)row * MODES;
#pragma unroll
    for (int c = 0; c < 4; ++c) {
        float tt = tw[1024 + t + 256 * c];
        float c0 = tw[2048 + t + 256 * c];
        float PA = fmaf(tt, o5[2][c], o5[0][c]);
        float PB = fmaf(tt, o5[3][c], o5[1][c]);
        xo[t + 256 * c] = __float2bfloat16(fmaf(c0, PB, PA));
    }
}

// ---------------- stage 2: channel mix (R7 coalesced mapping, bf16 xh) ----------------
// Wave = 64 contiguous bf16x8 k-chunks (1 KB xh, 2 KB w contiguous per access).
// grid (kt=2, bp=16, oz=16); thread: 8 k x 1 o x 2 b (pair b, 31-b).
__global__ __launch_bounds__(256) void mix_kernel(const __hip_bfloat16* __restrict__ xh,
                                                  const float* __restrict__ w,
                                                  __hip_bfloat16* __restrict__ y) {
    const int kl = threadIdx.x & 63;
    const int jg = threadIdx.x >> 6;          // 0..3
    const int k8 = blockIdx.x * 64 + kl;      // bf16x8 index, 0..127
    const int bp = blockIdx.y;                // 0..15 -> pair (bp, 31-bp)
    const int rb = (BATCH - 1) - bp;
    const int o  = blockIdx.z * 4 + jg;       // 0..63

    f32x4 accb0 = {0,0,0,0}, accb1 = {0,0,0,0};
    f32x4 accr0 = {0,0,0,0}, accr1 = {0,0,0,0};

    const __hip_bfloat16* xb  = xh + (size_t)(bp * CIN) * MODES + k8 * 8;
    const __hip_bfloat16* xrb = xh + (size_t)(rb * CIN) * MODES + k8 * 8;
    const float* wo = w + (size_t)o * MODES + k8 * 8;

#pragma unroll 4
    for (int i = 0; i < 32; ++i) {
        const int mi = 63 - i;
        bf16x8 xai = *(const bf16x8*)(xb  + (size_t)i  * MODES);
        bf16x8 xam = *(const bf16x8*)(xb  + (size_t)mi * MODES);
        bf16x8 xbi = *(const bf16x8*)(xrb + (size_t)i  * MODES);
        bf16x8 xbm = *(const bf16x8*)(xrb + (size_t)mi * MODES);
        f32x4 w1a = *(const f32x4*)(wo + (size_t)(i  * COUT) * MODES);
        f32x4 w1b = *(const f32x4*)(wo + (size_t)(i  * COUT) * MODES + 4);
        f32x4 w2a = *(const f32x4*)(wo + (size_t)(mi * COUT) * MODES);
        f32x4 w2b = *(const f32x4*)(wo + (size_t)(mi * COUT) * MODES + 4);

        f32x4 ai_lo, ai_hi, am_lo, am_hi, bi_lo, bi_hi, bm_lo, bm_hi;
        cvt8(xai, ai_lo, ai_hi);
        cvt8(xam, am_lo, am_hi);
        cvt8(xbi, bi_lo, bi_hi);
        cvt8(xbm, bm_lo, bm_hi);

        f32x4 sa0 = ai_lo + am_lo, sa1 = ai_hi + am_hi;
        f32x4 da0 = ai_lo - am_lo, da1 = ai_hi - am_hi;
        f32x4 sb0 = bi_lo + bm_lo, sb1 = bi_hi + bm_hi;
        f32x4 db0 = bi_lo - bm_lo, db1 = bi_hi - bm_hi;
        f32x4 wp0 = w1a + w2a, wm0 = w1a - w2a;
        f32x4 wp1 = w1b + w2b, wm1 = w1b - w2b;

        accb0 += sa0 * wp0 + db0 * wm0;
        accb1 += sa1 * wp1 + db1 * wm1;
        accr0 += sb0 * wp0 + da0 * wm0;
        accr1 += sb1 * wp1 + da1 * wm1;
    }

    bf16x8 vb = pack8(accb0 * 0.5f, accb1 * 0.5f);
    bf16x8 vr = pack8(accr0 * 0.5f, accr1 * 0.5f);
    *(bf16x8*)(y + (size_t)(bp * COUT + o) * MODES + k8 * 8) = vb;
    *(bf16x8*)(y + (size_t)(rb * COUT + o) * MODES + k8 * 8) = vr;
}

// ---------------- stage 3: iDHT MFMA GEMM, barrier-free all-register ----------------
// 64x64 tile, 2 waves, BK=32, grid 32x33. A-frags AND B-frags loaded straight from
// global (A gather pattern identical to the old LDS staging; B is frag-ordered c2f).
// 3-deep register pipeline, fully unrolled K-loop, zero __syncthreads.
__global__ __launch_bounds__(128) void idht_mfma(const __hip_bfloat16* __restrict__ yh,
                                                 const __hip_bfloat16* __restrict__ c2f,
                                                 float* __restrict__ out) {
    const int tid  = threadIdx.x;
    const int lane = tid & 63;
    const int wave = tid >> 6;
    const int rbase = blockIdx.x * 64;
    const int gn0   = blockIdx.y * 4;
    const int nbase = gn0 * 16;

    const char* ga = (const char*)yh + (size_t)rbase * 2048
                   + (size_t)(wave * 32 + (lane & 15)) * 2048 + (lane >> 4) * 16;
    const char* gb = (const char*)c2f + ((size_t)gn0 * 32 * 64 + lane) * 16;

    f32x4 acc[2][4];
#pragma unroll
    for (int mt = 0; mt < 2; ++mt)
#pragma unroll
        for (int nt = 0; nt < 4; ++nt) acc[mt][nt] = (f32x4){0.f, 0.f, 0.f, 0.f};

    bf16x8 af[3][2], bf[3][4];

#define LOADS(ks, s)                                                              \
    {                                                                             \
        _Pragma("unroll")                                                         \
        for (int mt = 0; mt < 2; ++mt)                                            \
            af[s][mt] = *(const bf16x8*)(ga + (size_t)mt * 16 * 2048 + (ks) * 64);\
        _Pragma("unroll")                                                         \
        for (int nt = 0; nt < 4; ++nt)                                            \
            bf[s][nt] = *(const bf16x8*)(gb + ((size_t)nt * 32 + (ks)) * 1024);   \
    }

    LOADS(0, 0)
    LOADS(1, 1)
    LOADS(2, 2)
#pragma unroll
    for (int ks = 0; ks < MODES / 32; ++ks) {
        const int s = ks % 3;
#pragma unroll
        for (int mt = 0; mt < 2; ++mt)
#pragma unroll
            for (int nt = 0; nt < 4; ++nt)
                acc[mt][nt] = __builtin_amdgcn_mfma_f32_16x16x32_bf16(af[s][mt], bf[s][nt], acc[mt][nt], 0, 0, 0);
        if (ks + 3 < MODES / 32) LOADS(ks + 3, s)
    }
#undef LOADS

    // epilogue: C/D layout col=lane&15, row=(lane>>4)*4+reg
    const bool full = (nbase + 64 <= KOUT);
#pragma unroll
    for (int mt = 0; mt < 2; ++mt) {
        int row = rbase + wave * 32 + mt * 16 + (lane >> 4) * 4;
#pragma unroll
        for (int nt = 0; nt < 4; ++nt) {
            int col = nbase + nt * 16 + (lane & 15);
            if (full || col < KOUT) {
#pragma unroll
                for (int r = 0; r < 4; ++r)
                    out[(size_t)(row + r) * KOUT + col] = acc[mt][nt][r];
            }
        }
    }
}

// ---------------- launch ----------------
extern "C" void kernel_launch(void* const* d_in, const int* in_sizes, int n_in,
                              void* d_out, int out_size, void* d_ws, size_t ws_size,
                              hipStream_t stream) {
    const float* x = (const float*)d_in[0];     // (32, 64, 4096)
    const float* w = (const float*)d_in[1];     // (64, 64, 1024)
    float* out = (float*)d_out;                 // (32, 64, 2049)

    float* tw = (float*)d_ws;                                  // 4096 f32
    __hip_bfloat16* xh  = (__hip_bfloat16*)(tw + NFFT);        // 2048*1024 bf16
    __hip_bfloat16* y   = xh + (size_t)BATCH * CIN * MODES;    // 2048*1024 bf16
    __hip_bfloat16* c2f = y + (size_t)BATCH * COUT * MODES;    // NPAD*1024 bf16

    fill_tables<<<(NCHUNK + NFFT + 255) / 256, 256, 0, stream>>>(tw, c2f);
    fht_kernel<<<BATCH * CIN, 256, 0, stream>>>(x, tw, xh);
    mix_kernel<<<dim3(2, 16, 16), 256, 0, stream>>>(xh, w, y);
    idht_mfma<<<dim3((BATCH * COUT) / 64, NPAD / 64), 128, 0, stream>>>(y, c2f, out);
}